// Round 2
// baseline (328.533 us; speedup 1.0000x reference)
//
#include <hip/hip_runtime.h>
#include <math.h>

#define HIDK 4096
#define NHQ 32
#define HD 128
#define CMAX 4608
#define CLEN 4096
#define SCALE 0.08838834764831845f   // 1/sqrt(128)

__device__ __forceinline__ float4 ld4(const float* p) { return *reinterpret_cast<const float4*>(p); }
__device__ __forceinline__ float dot4(float4 a, float4 b) { return a.x*b.x + a.y*b.y + a.z*b.z + a.w*b.w; }

// ---------------------------------------------------------------------------
// GEMM: out[bs, o] = sum_k X[bs,k] * W[o,k]   (M=16, K=4096)
// 256-thr block = 4 waves; each wave computes ONE output feature with the
// whole W row preloaded in two batches of 8 float4 (8 HBM loads in flight).
// ---------------------------------------------------------------------------
__global__ __launch_bounds__(256, 6) void gemm1_kernel(
    const float* __restrict__ X,
    const float* __restrict__ W1, const float* __restrict__ W2, const float* __restrict__ W3,
    int n1, int n2,
    float* __restrict__ o1, int os1,
    float* __restrict__ o2, int os2,
    float* __restrict__ o3, int os3)
{
  const int lane = threadIdx.x & 63;
  const int o = blockIdx.x * 4 + (threadIdx.x >> 6);

  const float* Wb; float* ob; int os;
  if (o < n1)           { Wb = W1 + (size_t)o * HIDK;            ob = o1 + o;            os = os1; }
  else if (o < n1 + n2) { const int f = o - n1;      Wb = W2 + (size_t)f * HIDK; ob = o2 + f; os = os2; }
  else                  { const int f = o - n1 - n2; Wb = W3 + (size_t)f * HIDK; ob = o3 + f; os = os3; }

  float acc[16];
  #pragma unroll
  for (int b = 0; b < 16; ++b) acc[b] = 0.f;

  #pragma unroll
  for (int h = 0; h < 2; ++h) {
    float4 w[8];
    #pragma unroll
    for (int i = 0; i < 8; ++i) w[i] = ld4(Wb + h * 2048 + i * 256 + lane * 4);
    #pragma unroll
    for (int i = 0; i < 8; ++i) {
      const int k0 = h * 2048 + i * 256 + lane * 4;
      #pragma unroll
      for (int b = 0; b < 16; ++b)
        acc[b] += dot4(ld4(X + (size_t)b * HIDK + k0), w[i]);
    }
  }

  #pragma unroll
  for (int m = 1; m < 64; m <<= 1)
    #pragma unroll
    for (int b = 0; b < 16; ++b) acc[b] += __shfl_xor(acc[b], m, 64);

  if (lane == 0) {
    #pragma unroll
    for (int b = 0; b < 16; ++b) ob[(size_t)b * os] = acc[b];
  }
}

// ---------------------------------------------------------------------------
// Attention over cache chunk. Block = 256 thr (4 waves), owns 8 rows
// (2 heads x 4 queries) x CH positions. grid = 32(b,kv) * 2(head-pair) * NCH.
// ---------------------------------------------------------------------------
template <int CH>
__global__ __launch_bounds__(256, 6) void attn_kernel(
    const float* __restrict__ qraw, const float* __restrict__ Kc, const float* __restrict__ Vc,
    const float* __restrict__ cosp, const float* __restrict__ sinp,
    float* __restrict__ partO, float* __restrict__ partM, float* __restrict__ partL)
{
  constexpr int NCH = CLEN / CH;
  __shared__ float qsh[8][128];
  __shared__ float P[CH][12];          // [pos][row 0..7], pad to 12

  const int tid = threadIdx.x, lane = tid & 63, w = tid >> 6;
  const int chunk = blockIdx.x % NCH;
  const int bh = blockIdx.x / NCH;     // bkv*2 + hp
  const int hp = bh & 1;
  const int bkv = bh >> 1;
  const int b = bkv >> 3, kv = bkv & 7;
  const int p0 = chunk * CH;
  const int h0 = kv * 4 + hp * 2;

  // prologue: RoPE(q)*SCALE for 8 rows
  #pragma unroll
  for (int e = tid; e < 1024; e += 256) {
    const int r = e >> 7, d = e & 127;
    const int hl = r >> 2, s = r & 3;
    const int h = h0 + hl;
    const float* qp = qraw + (size_t)(b * 4 + s) * HIDK + h * HD;
    const float c  = cosp[(b * 4 + s) * HD + d];
    const float sn = sinp[(b * 4 + s) * HD + d];
    const float sgn = (d < 64) ? -1.f : 1.f;
    qsh[r][d] = (qp[d] * c + sgn * qp[d ^ 64] * sn) * SCALE;
  }
  __syncthreads();

  // scores: wave w owns positions [w*CH/4, (w+1)*CH/4); lane = (dsub 0..31, psub 0..1)
  {
    const int dsub = lane & 31, psub = lane >> 5;
    float4 q[8];
    #pragma unroll
    for (int r = 0; r < 8; ++r) q[r] = ld4(&qsh[r][dsub * 4]);
    constexpr int PPW = CH / 4;
    const float* Kbase = Kc + ((size_t)(b * 8 + kv) * CMAX + p0 + w * PPW) * HD + dsub * 4;
    #pragma unroll 2
    for (int i = 0; i < PPW / 2; ++i) {
      const int pl = i * 2 + psub;
      const float4 k4 = ld4(Kbase + (size_t)pl * HD);
      float sc[8];
      #pragma unroll
      for (int r = 0; r < 8; ++r) sc[r] = dot4(k4, q[r]);
      #pragma unroll
      for (int m = 1; m < 32; m <<= 1)
        #pragma unroll
        for (int r = 0; r < 8; ++r) sc[r] += __shfl_xor(sc[r], m, 64);
      if (dsub == 0) {
        *(float4*)&P[w * PPW + pl][0] = make_float4(sc[0], sc[1], sc[2], sc[3]);
        *(float4*)&P[w * PPW + pl][4] = make_float4(sc[4], sc[5], sc[6], sc[7]);
      }
    }
  }
  __syncthreads();

  // chunk softmax: wave w owns rows 2w, 2w+1
  {
    constexpr int NPL = CH / 64;
    #pragma unroll
    for (int rr = 0; rr < 2; ++rr) {
      const int r = w * 2 + rr;
      float v[NPL];
      float mx = -INFINITY;
      #pragma unroll
      for (int k = 0; k < NPL; ++k) { v[k] = P[lane + 64 * k][r]; mx = fmaxf(mx, v[k]); }
      #pragma unroll
      for (int m = 1; m < 64; m <<= 1) mx = fmaxf(mx, __shfl_xor(mx, m, 64));
      float l = 0.f;
      #pragma unroll
      for (int k = 0; k < NPL; ++k) { v[k] = __expf(v[k] - mx); l += v[k]; }
      #pragma unroll
      for (int m = 1; m < 64; m <<= 1) l += __shfl_xor(l, m, 64);
      #pragma unroll
      for (int k = 0; k < NPL; ++k) P[lane + 64 * k][r] = v[k];
      if (lane == 0) {
        const int hl = r >> 2, s = r & 3, h = h0 + hl;
        const int row = (b * NHQ + h) * 4 + s;
        partM[row * NCH + chunk] = mx;
        partL[row * NCH + chunk] = l;
      }
    }
  }
  __syncthreads();

  // PV: wave w owns dims [w*32, w*32+32); lane halves split positions
  {
    const int dl = lane & 31, ph = lane >> 5;
    const int d = w * 32 + dl;
    float o[8];
    #pragma unroll
    for (int r = 0; r < 8; ++r) o[r] = 0.f;
    constexpr int HP = CH / 2;
    const float* Vbase = Vc + ((size_t)(b * 8 + kv) * CMAX + p0 + ph * HP) * HD + d;
    #pragma unroll 4
    for (int p = 0; p < HP; ++p) {
      const float vv = Vbase[(size_t)p * HD];
      const int pc = ph * HP + p;
      const float4 pa = *(const float4*)&P[pc][0];
      const float4 pb = *(const float4*)&P[pc][4];
      o[0] += pa.x * vv; o[1] += pa.y * vv; o[2] += pa.z * vv; o[3] += pa.w * vv;
      o[4] += pb.x * vv; o[5] += pb.y * vv; o[6] += pb.z * vv; o[7] += pb.w * vv;
    }
    #pragma unroll
    for (int r = 0; r < 8; ++r) o[r] += __shfl_xor(o[r], 32, 64);
    if (ph == 0) {
      #pragma unroll
      for (int r = 0; r < 8; ++r) {
        const int hl = r >> 2, s = r & 3, h = h0 + hl;
        const size_t row = (size_t)(b * NHQ + h) * 4 + s;
        partO[(row * NCH + chunk) * HD + d] = o[r];
      }
    }
  }
}

// ---------------------------------------------------------------------------
// Flash-combine NCH chunk partials + <=4 new causal tokens. 512 blocks x 64.
// ---------------------------------------------------------------------------
template <int NCH>
__global__ __launch_bounds__(64) void combine_kernel(
    const float* __restrict__ qraw, const float* __restrict__ kraw, const float* __restrict__ vraw,
    const float* __restrict__ cosp, const float* __restrict__ sinp,
    const float* __restrict__ partO, const float* __restrict__ partM, const float* __restrict__ partL,
    float* __restrict__ attn)
{
  const int bid = blockIdx.x;             // ((b*32 + h)*4 + s)
  const int s = bid & 3;
  const int h = (bid >> 2) & 31;
  const int b = bid >> 7;
  const int kv = h >> 2;
  const int lane = threadIdx.x;
  const int d0 = lane * 2;

  float mc[NCH], lc[NCH];
  float M = -INFINITY;
  #pragma unroll
  for (int c = 0; c < NCH; ++c) {
    mc[c] = partM[bid * NCH + c];
    lc[c] = partL[bid * NCH + c];
    M = fmaxf(M, mc[c]);
  }

  float qr0, qr1;
  {
    const float* qp = qraw + (size_t)(b * 4 + s) * HIDK + h * HD;
    const float c0 = cosp[(b * 4 + s) * HD + d0],     sn0 = sinp[(b * 4 + s) * HD + d0];
    const float c1 = cosp[(b * 4 + s) * HD + d0 + 1], sn1 = sinp[(b * 4 + s) * HD + d0 + 1];
    const float sg0 = (d0 < 64) ? -1.f : 1.f;
    const float sg1 = ((d0 + 1) < 64) ? -1.f : 1.f;
    qr0 = (qp[d0] * c0 + sg0 * qp[d0 ^ 64] * sn0) * SCALE;
    qr1 = (qp[d0 + 1] * c1 + sg1 * qp[(d0 + 1) ^ 64] * sn1) * SCALE;
  }

  float sj[4] = {0.f, 0.f, 0.f, 0.f};
  float Mp = M;
  #pragma unroll
  for (int j = 0; j < 4; ++j) {
    if (j <= s) {
      const float* kp = kraw + (size_t)(b * 4 + j) * 1024 + kv * HD;
      const float c0 = cosp[(b * 4 + j) * HD + d0],     sn0 = sinp[(b * 4 + j) * HD + d0];
      const float c1 = cosp[(b * 4 + j) * HD + d0 + 1], sn1 = sinp[(b * 4 + j) * HD + d0 + 1];
      const float sg0 = (d0 < 64) ? -1.f : 1.f;
      const float sg1 = ((d0 + 1) < 64) ? -1.f : 1.f;
      const float kr0 = kp[d0] * c0 + sg0 * kp[d0 ^ 64] * sn0;
      const float kr1 = kp[d0 + 1] * c1 + sg1 * kp[(d0 + 1) ^ 64] * sn1;
      float part = qr0 * kr0 + qr1 * kr1;
      #pragma unroll
      for (int m = 1; m < 64; m <<= 1) part += __shfl_xor(part, m, 64);
      sj[j] = part;
      Mp = fmaxf(Mp, part);
    }
  }

  float a[NCH];
  #pragma unroll
  for (int c = 0; c < NCH; ++c) a[c] = __expf(mc[c] - Mp);

  float ltot = 0.f, O0 = 0.f, O1 = 0.f;
  #pragma unroll 4
  for (int c = 0; c < NCH; ++c) {
    ltot += lc[c] * a[c];
    const float2 v = *(const float2*)&partO[((size_t)bid * NCH + c) * HD + d0];
    O0 += a[c] * v.x;
    O1 += a[c] * v.y;
  }
  #pragma unroll
  for (int j = 0; j < 4; ++j) {
    if (j <= s) {
      const float e = __expf(sj[j] - Mp);
      ltot += e;
      const float* vp = vraw + (size_t)(b * 4 + j) * 1024 + kv * HD + d0;
      O0 += e * vp[0];
      O1 += e * vp[1];
    }
  }
  const float inv = 1.f / ltot;
  *(float2*)&attn[(size_t)(b * 4 + s) * HIDK + h * HD + d0] = make_float2(O0 * inv, O1 * inv);
}

// ---------------------------------------------------------------------------
extern "C" void kernel_launch(void* const* d_in, const int* in_sizes, int n_in,
                              void* d_out, int out_size, void* d_ws, size_t ws_size,
                              hipStream_t stream)
{
  const float* hid  = (const float*)d_in[0];
  const float* cosp = (const float*)d_in[1];
  const float* sinp = (const float*)d_in[2];
  const float* Kc   = (const float*)d_in[3];
  const float* Vc   = (const float*)d_in[4];
  const float* Wq   = (const float*)d_in[5];
  const float* Wk   = (const float*)d_in[6];
  const float* Wv   = (const float*)d_in[7];
  const float* Wo   = (const float*)d_in[8];
  float* out = (float*)d_out;

  float* ws    = (float*)d_ws;
  float* qraw  = ws;                 // 16*4096  = 65536
  float* kraw  = ws + 65536;         // 16*1024  = 16384
  float* vraw  = ws + 81920;         // 16*1024  = 16384
  float* attn  = ws + 98304;         // 16*4096  = 65536
  float* partO = ws + 163840;        // 512*NCH*128
  // NCH=32 total: 163840 + 2097152 + 2*16384 = 2293760 floats = 9.18 MB
  // NCH=16 total: 1228800 floats = 4.92 MB (proven to fit last round)
  const bool big = ws_size >= (size_t)2293760 * sizeof(float);
  const int nch = big ? 32 : 16;
  float* partM = partO + (size_t)512 * nch * 128;
  float* partL = partM + (size_t)512 * nch;

  // A: QKV projection (raw, un-roped)
  gemm1_kernel<<<1536, 256, 0, stream>>>(hid, Wq, Wk, Wv, 4096, 1024,
                                         qraw, 4096, kraw, 1024, vraw, 1024);
  // B: attention over cached positions
  if (big)
    attn_kernel<128><<<64 * 32, 256, 0, stream>>>(qraw, Kc, Vc, cosp, sinp, partO, partM, partL);
  else
    attn_kernel<256><<<64 * 16, 256, 0, stream>>>(qraw, Kc, Vc, cosp, sinp, partO, partM, partL);
  // C: combine + new causal tokens
  if (big)
    combine_kernel<32><<<512, 64, 0, stream>>>(qraw, kraw, vraw, cosp, sinp, partO, partM, partL, attn);
  else
    combine_kernel<16><<<512, 64, 0, stream>>>(qraw, kraw, vraw, cosp, sinp, partO, partM, partL, attn);
  // D: output projection
  gemm1_kernel<<<1024, 256, 0, stream>>>(attn, Wo, Wo, Wo, 4096, 0,
                                         out, 4096, out, 4096, out, 4096);
}

// Round 3
// 181.962 us; speedup vs baseline: 1.8055x; 1.8055x over previous
//
#include <hip/hip_runtime.h>
#include <math.h>

#define HIDK 4096
#define NHQ 32
#define HD 128
#define CMAX 4608
#define CLEN 4096
#define SCALE 0.08838834764831845f   // 1/sqrt(128)

__device__ __forceinline__ float4 ld4(const float* p) { return *reinterpret_cast<const float4*>(p); }
__device__ __forceinline__ float dot4(float4 a, float4 b) { return a.x*b.x + a.y*b.y + a.z*b.z + a.w*b.w; }

// ---------------------------------------------------------------------------
// GEMM: out[bs, o] = sum_k X[bs,k] * W[o,k]   (M=16, K=4096)
// 256-thr block = 4 waves; each wave computes TWO output features.
// acc = 32 VGPR, no launch_bounds squeeze -> no spills.
// ---------------------------------------------------------------------------
__global__ __launch_bounds__(256) void gemm2_kernel(
    const float* __restrict__ X,
    const float* __restrict__ W1, const float* __restrict__ W2, const float* __restrict__ W3,
    int n1, int n2,
    float* __restrict__ o1, int os1,
    float* __restrict__ o2, int os2,
    float* __restrict__ o3, int os3)
{
  const int lane = threadIdx.x & 63;
  const int o = blockIdx.x * 8 + (threadIdx.x >> 6) * 2;   // segment boundaries are even

  const float* Wb; float* ob; int os;
  if (o < n1)           { Wb = W1 + (size_t)o * HIDK;            ob = o1 + o;            os = os1; }
  else if (o < n1 + n2) { const int f = o - n1;      Wb = W2 + (size_t)f * HIDK; ob = o2 + f; os = os2; }
  else                  { const int f = o - n1 - n2; Wb = W3 + (size_t)f * HIDK; ob = o3 + f; os = os3; }

  float acc0[16], acc1[16];
  #pragma unroll
  for (int b = 0; b < 16; ++b) { acc0[b] = 0.f; acc1[b] = 0.f; }

  #pragma unroll 2
  for (int i = 0; i < 16; ++i) {
    const int k0 = i * 256 + lane * 4;
    const float4 w0 = ld4(Wb + k0);
    const float4 w1 = ld4(Wb + HIDK + k0);
    #pragma unroll
    for (int b = 0; b < 16; ++b) {
      const float4 x = ld4(X + (size_t)b * HIDK + k0);
      acc0[b] += dot4(x, w0);
      acc1[b] += dot4(x, w1);
    }
  }

  #pragma unroll
  for (int m = 1; m < 64; m <<= 1)
    #pragma unroll
    for (int b = 0; b < 16; ++b) {
      acc0[b] += __shfl_xor(acc0[b], m, 64);
      acc1[b] += __shfl_xor(acc1[b], m, 64);
    }

  if (lane == 0) {
    #pragma unroll
    for (int b = 0; b < 16; ++b) {
      ob[(size_t)b * os]     = acc0[b];
      ob[(size_t)b * os + 1] = acc1[b];
    }
  }
}

// ---------------------------------------------------------------------------
// Attention over cache chunk. Block = 256 thr (4 waves), owns 8 rows
// (2 heads x 4 queries) x CH positions. grid = 32(b,kv) * 2(head-pair) * NCH.
// ---------------------------------------------------------------------------
template <int CH>
__global__ __launch_bounds__(256) void attn_kernel(
    const float* __restrict__ qraw, const float* __restrict__ Kc, const float* __restrict__ Vc,
    const float* __restrict__ cosp, const float* __restrict__ sinp,
    float* __restrict__ partO, float* __restrict__ partM, float* __restrict__ partL)
{
  constexpr int NCH = CLEN / CH;
  __shared__ float qsh[8][128];
  __shared__ float P[CH][12];          // [pos][row 0..7], pad to 12

  const int tid = threadIdx.x, lane = tid & 63, w = tid >> 6;
  const int chunk = blockIdx.x % NCH;
  const int bh = blockIdx.x / NCH;     // bkv*2 + hp
  const int hp = bh & 1;
  const int bkv = bh >> 1;
  const int b = bkv >> 3, kv = bkv & 7;
  const int p0 = chunk * CH;
  const int h0 = kv * 4 + hp * 2;

  // prologue: RoPE(q)*SCALE for 8 rows
  #pragma unroll
  for (int e = tid; e < 1024; e += 256) {
    const int r = e >> 7, d = e & 127;
    const int hl = r >> 2, s = r & 3;
    const int h = h0 + hl;
    const float* qp = qraw + (size_t)(b * 4 + s) * HIDK + h * HD;
    const float c  = cosp[(b * 4 + s) * HD + d];
    const float sn = sinp[(b * 4 + s) * HD + d];
    const float sgn = (d < 64) ? -1.f : 1.f;
    qsh[r][d] = (qp[d] * c + sgn * qp[d ^ 64] * sn) * SCALE;
  }
  __syncthreads();

  // scores: wave w owns positions [w*CH/4, (w+1)*CH/4); lane = (dsub 0..31, psub 0..1)
  {
    const int dsub = lane & 31, psub = lane >> 5;
    float4 q[8];
    #pragma unroll
    for (int r = 0; r < 8; ++r) q[r] = ld4(&qsh[r][dsub * 4]);
    constexpr int PPW = CH / 4;
    const float* Kbase = Kc + ((size_t)(b * 8 + kv) * CMAX + p0 + w * PPW) * HD + dsub * 4;
    #pragma unroll 2
    for (int i = 0; i < PPW / 2; ++i) {
      const int pl = i * 2 + psub;
      const float4 k4 = ld4(Kbase + (size_t)pl * HD);
      float sc[8];
      #pragma unroll
      for (int r = 0; r < 8; ++r) sc[r] = dot4(k4, q[r]);
      #pragma unroll
      for (int m = 1; m < 32; m <<= 1)
        #pragma unroll
        for (int r = 0; r < 8; ++r) sc[r] += __shfl_xor(sc[r], m, 64);
      if (dsub == 0) {
        *(float4*)&P[w * PPW + pl][0] = make_float4(sc[0], sc[1], sc[2], sc[3]);
        *(float4*)&P[w * PPW + pl][4] = make_float4(sc[4], sc[5], sc[6], sc[7]);
      }
    }
  }
  __syncthreads();

  // chunk softmax: wave w owns rows 2w, 2w+1
  {
    constexpr int NPL = CH / 64;
    #pragma unroll
    for (int rr = 0; rr < 2; ++rr) {
      const int r = w * 2 + rr;
      float v[NPL];
      float mx = -INFINITY;
      #pragma unroll
      for (int k = 0; k < NPL; ++k) { v[k] = P[lane + 64 * k][r]; mx = fmaxf(mx, v[k]); }
      #pragma unroll
      for (int m = 1; m < 64; m <<= 1) mx = fmaxf(mx, __shfl_xor(mx, m, 64));
      float l = 0.f;
      #pragma unroll
      for (int k = 0; k < NPL; ++k) { v[k] = __expf(v[k] - mx); l += v[k]; }
      #pragma unroll
      for (int m = 1; m < 64; m <<= 1) l += __shfl_xor(l, m, 64);
      #pragma unroll
      for (int k = 0; k < NPL; ++k) P[lane + 64 * k][r] = v[k];
      if (lane == 0) {
        const int hl = r >> 2, s = r & 3, h = h0 + hl;
        const int row = (b * NHQ + h) * 4 + s;
        partM[row * NCH + chunk] = mx;
        partL[row * NCH + chunk] = l;
      }
    }
  }
  __syncthreads();

  // PV: wave w owns dims [w*32, w*32+32); lane halves split positions
  {
    const int dl = lane & 31, ph = lane >> 5;
    const int d = w * 32 + dl;
    float o[8];
    #pragma unroll
    for (int r = 0; r < 8; ++r) o[r] = 0.f;
    constexpr int HP = CH / 2;
    const float* Vbase = Vc + ((size_t)(b * 8 + kv) * CMAX + p0 + ph * HP) * HD + d;
    #pragma unroll 4
    for (int p = 0; p < HP; ++p) {
      const float vv = Vbase[(size_t)p * HD];
      const int pc = ph * HP + p;
      const float4 pa = *(const float4*)&P[pc][0];
      const float4 pb = *(const float4*)&P[pc][4];
      o[0] += pa.x * vv; o[1] += pa.y * vv; o[2] += pa.z * vv; o[3] += pa.w * vv;
      o[4] += pb.x * vv; o[5] += pb.y * vv; o[6] += pb.z * vv; o[7] += pb.w * vv;
    }
    #pragma unroll
    for (int r = 0; r < 8; ++r) o[r] += __shfl_xor(o[r], 32, 64);
    if (ph == 0) {
      #pragma unroll
      for (int r = 0; r < 8; ++r) {
        const int hl = r >> 2, s = r & 3, h = h0 + hl;
        const size_t row = (size_t)(b * NHQ + h) * 4 + s;
        partO[(row * NCH + chunk) * HD + d] = o[r];
      }
    }
  }
}

// ---------------------------------------------------------------------------
// Flash-combine NCH chunk partials + <=4 new causal tokens. 512 blocks x 64.
// Array-free (no mc[]/lc[]/a[] -> no spill risk at NCH=32).
// ---------------------------------------------------------------------------
template <int NCH>
__global__ __launch_bounds__(64) void combine_kernel(
    const float* __restrict__ qraw, const float* __restrict__ kraw, const float* __restrict__ vraw,
    const float* __restrict__ cosp, const float* __restrict__ sinp,
    const float* __restrict__ partO, const float* __restrict__ partM, const float* __restrict__ partL,
    float* __restrict__ attn)
{
  const int bid = blockIdx.x;             // ((b*32 + h)*4 + s)
  const int s = bid & 3;
  const int h = (bid >> 2) & 31;
  const int b = bid >> 7;
  const int kv = h >> 2;
  const int lane = threadIdx.x;
  const int d0 = lane * 2;

  float M = -INFINITY;
  #pragma unroll 4
  for (int c = 0; c < NCH; ++c) M = fmaxf(M, partM[bid * NCH + c]);

  float qr0, qr1;
  {
    const float* qp = qraw + (size_t)(b * 4 + s) * HIDK + h * HD;
    const float c0 = cosp[(b * 4 + s) * HD + d0],     sn0 = sinp[(b * 4 + s) * HD + d0];
    const float c1 = cosp[(b * 4 + s) * HD + d0 + 1], sn1 = sinp[(b * 4 + s) * HD + d0 + 1];
    const float sg0 = (d0 < 64) ? -1.f : 1.f;
    const float sg1 = ((d0 + 1) < 64) ? -1.f : 1.f;
    qr0 = (qp[d0] * c0 + sg0 * qp[d0 ^ 64] * sn0) * SCALE;
    qr1 = (qp[d0 + 1] * c1 + sg1 * qp[(d0 + 1) ^ 64] * sn1) * SCALE;
  }

  float sj[4] = {0.f, 0.f, 0.f, 0.f};
  float Mp = M;
  #pragma unroll
  for (int j = 0; j < 4; ++j) {
    if (j <= s) {
      const float* kp = kraw + (size_t)(b * 4 + j) * 1024 + kv * HD;
      const float c0 = cosp[(b * 4 + j) * HD + d0],     sn0 = sinp[(b * 4 + j) * HD + d0];
      const float c1 = cosp[(b * 4 + j) * HD + d0 + 1], sn1 = sinp[(b * 4 + j) * HD + d0 + 1];
      const float sg0 = (d0 < 64) ? -1.f : 1.f;
      const float sg1 = ((d0 + 1) < 64) ? -1.f : 1.f;
      const float kr0 = kp[d0] * c0 + sg0 * kp[d0 ^ 64] * sn0;
      const float kr1 = kp[d0 + 1] * c1 + sg1 * kp[(d0 + 1) ^ 64] * sn1;
      float part = qr0 * kr0 + qr1 * kr1;
      #pragma unroll
      for (int m = 1; m < 64; m <<= 1) part += __shfl_xor(part, m, 64);
      sj[j] = part;
      Mp = fmaxf(Mp, part);
    }
  }

  float ltot = 0.f, O0 = 0.f, O1 = 0.f;
  #pragma unroll 4
  for (int c = 0; c < NCH; ++c) {
    const float a = __expf(partM[bid * NCH + c] - Mp);
    ltot += partL[bid * NCH + c] * a;
    const float2 v = *(const float2*)&partO[((size_t)bid * NCH + c) * HD + d0];
    O0 += a * v.x;
    O1 += a * v.y;
  }
  #pragma unroll
  for (int j = 0; j < 4; ++j) {
    if (j <= s) {
      const float e = __expf(sj[j] - Mp);
      ltot += e;
      const float* vp = vraw + (size_t)(b * 4 + j) * 1024 + kv * HD + d0;
      O0 += e * vp[0];
      O1 += e * vp[1];
    }
  }
  const float inv = 1.f / ltot;
  *(float2*)&attn[(size_t)(b * 4 + s) * HIDK + h * HD + d0] = make_float2(O0 * inv, O1 * inv);
}

// ---------------------------------------------------------------------------
extern "C" void kernel_launch(void* const* d_in, const int* in_sizes, int n_in,
                              void* d_out, int out_size, void* d_ws, size_t ws_size,
                              hipStream_t stream)
{
  const float* hid  = (const float*)d_in[0];
  const float* cosp = (const float*)d_in[1];
  const float* sinp = (const float*)d_in[2];
  const float* Kc   = (const float*)d_in[3];
  const float* Vc   = (const float*)d_in[4];
  const float* Wq   = (const float*)d_in[5];
  const float* Wk   = (const float*)d_in[6];
  const float* Wv   = (const float*)d_in[7];
  const float* Wo   = (const float*)d_in[8];
  float* out = (float*)d_out;

  float* ws    = (float*)d_ws;
  float* qraw  = ws;                 // 16*4096  = 65536
  float* kraw  = ws + 65536;         // 16*1024  = 16384
  float* vraw  = ws + 81920;         // 16*1024  = 16384
  float* attn  = ws + 98304;         // 16*4096  = 65536
  float* partO = ws + 163840;        // 512*NCH*128
  const bool big = ws_size >= (size_t)2293760 * sizeof(float);
  const int nch = big ? 32 : 16;
  float* partM = partO + (size_t)512 * nch * 128;
  float* partL = partM + (size_t)512 * nch;

  // A: QKV projection (raw, un-roped): 6144 outputs, 8 per block
  gemm2_kernel<<<768, 256, 0, stream>>>(hid, Wq, Wk, Wv, 4096, 1024,
                                        qraw, 4096, kraw, 1024, vraw, 1024);
  // B: attention over cached positions
  if (big)
    attn_kernel<128><<<64 * 32, 256, 0, stream>>>(qraw, Kc, Vc, cosp, sinp, partO, partM, partL);
  else
    attn_kernel<256><<<64 * 16, 256, 0, stream>>>(qraw, Kc, Vc, cosp, sinp, partO, partM, partL);
  // C: combine + new causal tokens
  if (big)
    combine_kernel<32><<<512, 64, 0, stream>>>(qraw, kraw, vraw, cosp, sinp, partO, partM, partL, attn);
  else
    combine_kernel<16><<<512, 64, 0, stream>>>(qraw, kraw, vraw, cosp, sinp, partO, partM, partL, attn);
  // D: output projection: 4096 outputs
  gemm2_kernel<<<512, 256, 0, stream>>>(attn, Wo, Wo, Wo, 4096, 0,
                                        out, 4096, out, 4096, out, 4096);
}

// Round 4
// 136.306 us; speedup vs baseline: 2.4103x; 1.3350x over previous
//
#include <hip/hip_runtime.h>
#include <math.h>

#define HIDK 4096
#define NHQ 32
#define HD 128
#define CMAX 4608
#define CLEN 4096
#define NCH 32          // 128-position chunks
#define SCALE 0.08838834764831845f   // 1/sqrt(128)

__device__ __forceinline__ float4 ld4(const float* p) { return *reinterpret_cast<const float4*>(p); }
__device__ __forceinline__ float dot4(float4 a, float4 b) { return a.x*b.x + a.y*b.y + a.z*b.z + a.w*b.w; }
// XOR-swizzled float index into a 64x128 fp32 LDS tile (T2; 2-way max = free)
__device__ __forceinline__ int swz(int row, int colf) { return row * 128 + (colf ^ ((row & 31) << 2)); }

// ---------------------------------------------------------------------------
// GEMM: out[bs,o] = sum_k X[bs,k]*W[o,k]  (M=16, K=4096), 4 waves/block,
// 2 outputs/wave, X double-buffered through LDS (1 barrier per 256-K tile).
// ---------------------------------------------------------------------------
__global__ __launch_bounds__(256) void gemm3_kernel(
    const float* __restrict__ X,
    const float* __restrict__ W1, const float* __restrict__ W2, const float* __restrict__ W3,
    int n1, int n2,
    float* __restrict__ o1, int os1,
    float* __restrict__ o2, int os2,
    float* __restrict__ o3, int os3)
{
  __shared__ float Xs[2][16][256];    // 2 x 16KB

  const int tid = threadIdx.x, lane = tid & 63, w = tid >> 6;
  const int o = blockIdx.x * 8 + w * 2;

  const float* Wb; float* ob; int os;
  if (o < n1)           { Wb = W1 + (size_t)o * HIDK;            ob = o1 + o;            os = os1; }
  else if (o < n1 + n2) { const int f = o - n1;      Wb = W2 + (size_t)f * HIDK; ob = o2 + f; os = os2; }
  else                  { const int f = o - n1 - n2; Wb = W3 + (size_t)f * HIDK; ob = o3 + f; os = os3; }

  const int xr = tid >> 6;            // reuse w: 4 rows base per j-step? no: staging index
  const int sr = tid >> 4;            // 16 threads per row-quarter... (see below)
  (void)xr; (void)sr;

  // staging map: idx = tid + j*256, j=0..3 -> row = idx>>6 (0..15), col = (idx&63)*4
  const int strow = tid >> 6;         // + j*4 rows per step
  const int stcol = (tid & 63) * 4;

  float acc0[16], acc1[16];
  #pragma unroll
  for (int b = 0; b < 16; ++b) { acc0[b] = 0.f; acc1[b] = 0.f; }

  // stage tile 0
  #pragma unroll
  for (int j = 0; j < 4; ++j)
    *(float4*)&Xs[0][strow + j * 4][stcol] = ld4(X + (size_t)(strow + j * 4) * HIDK + stcol);

  int cur = 0;
  #pragma unroll 2
  for (int kt = 0; kt < 16; ++kt) {
    const float4 w0 = ld4(Wb + (size_t)kt * 256 + lane * 4);
    const float4 w1 = ld4(Wb + HIDK + (size_t)kt * 256 + lane * 4);
    float4 g[4];
    if (kt < 15) {
      #pragma unroll
      for (int j = 0; j < 4; ++j)
        g[j] = ld4(X + (size_t)(strow + j * 4) * HIDK + (kt + 1) * 256 + stcol);
    }
    __syncthreads();                  // Xs[cur] ready
    #pragma unroll
    for (int b = 0; b < 16; ++b) {
      const float4 x4 = *(const float4*)&Xs[cur][b][lane * 4];
      acc0[b] += dot4(x4, w0);
      acc1[b] += dot4(x4, w1);
    }
    if (kt < 15) {
      #pragma unroll
      for (int j = 0; j < 4; ++j)
        *(float4*)&Xs[cur ^ 1][strow + j * 4][stcol] = g[j];
    }
    cur ^= 1;
  }

  #pragma unroll
  for (int m = 1; m < 64; m <<= 1)
    #pragma unroll
    for (int b = 0; b < 16; ++b) {
      acc0[b] += __shfl_xor(acc0[b], m, 64);
      acc1[b] += __shfl_xor(acc1[b], m, 64);
    }
  if (lane == 0) {
    #pragma unroll
    for (int b = 0; b < 16; ++b) {
      ob[(size_t)b * os]     = acc0[b];
      ob[(size_t)b * os + 1] = acc1[b];
    }
  }
}

// ---------------------------------------------------------------------------
// Attention: block = (b,kv) x 128-pos chunk, 16 rows (4 heads x 4 q), 4 waves.
// K/V staged via one swizzled 32KB LDS tile (two 64-pos sub-tiles).
// Scores lane-local (pos, dim-quarter) -> only 2 shuffle steps / 16 positions.
// ---------------------------------------------------------------------------
__global__ __launch_bounds__(256) void attn2_kernel(
    const float* __restrict__ qraw, const float* __restrict__ Kc, const float* __restrict__ Vc,
    const float* __restrict__ cosp, const float* __restrict__ sinp,
    float* __restrict__ partO, float* __restrict__ partM, float* __restrict__ partL)
{
  __shared__ float qsh[16][128];      // 8KB  RoPE'd * SCALE
  __shared__ float KV[64 * 128];      // 32KB swizzled, reused K0/K1/V0/V1
  __shared__ float P[128][20];        // 10KB scores -> probs

  const int tid = threadIdx.x, lane = tid & 63, w = tid >> 6;
  const int chunk = blockIdx.x & 31, bkv = blockIdx.x >> 5;
  const int b = bkv >> 3, kv = bkv & 7;
  const int p0 = chunk * 128;

  const float* Kbase = Kc + ((size_t)(b * 8 + kv) * CMAX + p0) * HD;
  const float* Vbase = Vc + ((size_t)(b * 8 + kv) * CMAX + p0) * HD;
  const int c0 = (tid & 31) * 4, r0 = tid >> 5;   // staging map: 32 thr/row

  // prologue: qsh = RoPE(q)*SCALE, rows r = hl*4 + s
  #pragma unroll
  for (int j = 0; j < 8; ++j) {
    const int e = tid + j * 256;
    const int r = e >> 7, d = e & 127;
    const int s = r & 3, hl = r >> 2;
    const float* qp = qraw + (size_t)(b * 4 + s) * HIDK + (kv * 4 + hl) * HD;
    const float c  = cosp[(b * 4 + s) * HD + d];
    const float sn = sinp[(b * 4 + s) * HD + d];
    const float sgn = (d < 64) ? -1.f : 1.f;
    qsh[r][d] = (qp[d] * c + sgn * qp[d ^ 64] * sn) * SCALE;
  }
  // stage K sub-tile 0
  #pragma unroll
  for (int j = 0; j < 8; ++j) {
    const int r = r0 + j * 8;
    *(float4*)&KV[swz(r, c0)] = ld4(Kbase + (size_t)r * HD + c0);
  }
  __syncthreads();

  // ---- scores for sub-tile t: wave owns 16 positions, lane = (pos16, quart) ----
  const int pos16 = lane & 15, quart = lane >> 4;
  const int prow = w * 16 + pos16;

  #pragma unroll
  for (int t = 0; t < 2; ++t) {
    float sc[16];
    #pragma unroll
    for (int r = 0; r < 16; ++r) sc[r] = 0.f;
    #pragma unroll
    for (int d4 = 0; d4 < 8; ++d4) {
      const int kcol = quart * 32 + d4 * 4;
      const float4 k4 = *(const float4*)&KV[swz(prow, kcol)];
      #pragma unroll
      for (int r = 0; r < 16; ++r)
        sc[r] += dot4(k4, *(const float4*)&qsh[r][kcol]);
    }
    #pragma unroll
    for (int r = 0; r < 16; ++r) {
      sc[r] += __shfl_xor(sc[r], 16, 64);
      sc[r] += __shfl_xor(sc[r], 32, 64);
    }
    if (lane < 16) {
      #pragma unroll
      for (int r = 0; r < 16; ++r) P[t * 64 + prow][r] = sc[r];
    }
    __syncthreads();
    if (t == 0) {   // stage K sub-tile 1
      #pragma unroll
      for (int j = 0; j < 8; ++j) {
        const int r = r0 + j * 8;
        *(float4*)&KV[swz(r, c0)] = ld4(Kbase + (size_t)(64 + r) * HD + c0);
      }
      __syncthreads();
    }
  }

  // ---- issue V0 loads early, softmax over 128 positions (4 rows per wave) ----
  float4 g[8];
  #pragma unroll
  for (int j = 0; j < 8; ++j)
    g[j] = ld4(Vbase + (size_t)(r0 + j * 8) * HD + c0);

  #pragma unroll
  for (int rr = 0; rr < 4; ++rr) {
    const int r = w * 4 + rr;
    float v0 = P[lane][r], v1 = P[lane + 64][r];
    float mx = fmaxf(v0, v1);
    #pragma unroll
    for (int m = 1; m < 64; m <<= 1) mx = fmaxf(mx, __shfl_xor(mx, m, 64));
    v0 = __expf(v0 - mx);
    v1 = __expf(v1 - mx);
    P[lane][r] = v0;
    P[lane + 64][r] = v1;
    float l = v0 + v1;
    #pragma unroll
    for (int m = 1; m < 64; m <<= 1) l += __shfl_xor(l, m, 64);
    if (lane == 0) {
      const int row = (b * NHQ + kv * 4 + (r >> 2)) * 4 + (r & 3);
      partM[row * NCH + chunk] = mx;
      partL[row * NCH + chunk] = l;
    }
  }
  #pragma unroll
  for (int j = 0; j < 8; ++j)
    *(float4*)&KV[swz(r0 + j * 8, c0)] = g[j];
  __syncthreads();

  // ---- PV: wave owns rows w*4..w*4+3, lane = (dim-quad, pos-parity) ----
  const int ph = lane >> 5, vc0 = (lane & 31) * 4;
  float4 o[4];
  #pragma unroll
  for (int rr = 0; rr < 4; ++rr) o[rr] = make_float4(0.f, 0.f, 0.f, 0.f);

  #pragma unroll
  for (int t = 0; t < 2; ++t) {
    #pragma unroll 4
    for (int i = 0; i < 32; ++i) {
      const int pr = 2 * i + ph;
      const float4 v4 = *(const float4*)&KV[swz(pr, vc0)];
      const float4 p4 = *(const float4*)&P[t * 64 + pr][w * 4];
      o[0].x += p4.x * v4.x; o[0].y += p4.x * v4.y; o[0].z += p4.x * v4.z; o[0].w += p4.x * v4.w;
      o[1].x += p4.y * v4.x; o[1].y += p4.y * v4.y; o[1].z += p4.y * v4.z; o[1].w += p4.y * v4.w;
      o[2].x += p4.z * v4.x; o[2].y += p4.z * v4.y; o[2].z += p4.z * v4.z; o[2].w += p4.z * v4.w;
      o[3].x += p4.w * v4.x; o[3].y += p4.w * v4.y; o[3].z += p4.w * v4.z; o[3].w += p4.w * v4.w;
    }
    if (t == 0) {   // stage V sub-tile 1
      __syncthreads();
      #pragma unroll
      for (int j = 0; j < 8; ++j) {
        const int r = r0 + j * 8;
        *(float4*)&KV[swz(r, c0)] = ld4(Vbase + (size_t)(64 + r) * HD + c0);
      }
      __syncthreads();
    }
  }

  // epilogue: combine position-parities, write partials
  #pragma unroll
  for (int rr = 0; rr < 4; ++rr) {
    o[rr].x += __shfl_xor(o[rr].x, 32, 64);
    o[rr].y += __shfl_xor(o[rr].y, 32, 64);
    o[rr].z += __shfl_xor(o[rr].z, 32, 64);
    o[rr].w += __shfl_xor(o[rr].w, 32, 64);
  }
  if (lane < 32) {
    #pragma unroll
    for (int rr = 0; rr < 4; ++rr) {
      const int r = w * 4 + rr;
      const int row = (b * NHQ + kv * 4 + (r >> 2)) * 4 + (r & 3);
      *(float4*)&partO[((size_t)row * NCH + chunk) * HD + lane * 4] = o[rr];
    }
  }
}

// ---------------------------------------------------------------------------
// Flash-combine 32 chunk partials + <=4 new causal tokens. 512 blocks x 64.
// ---------------------------------------------------------------------------
__global__ __launch_bounds__(64) void combine_kernel(
    const float* __restrict__ qraw, const float* __restrict__ kraw, const float* __restrict__ vraw,
    const float* __restrict__ cosp, const float* __restrict__ sinp,
    const float* __restrict__ partO, const float* __restrict__ partM, const float* __restrict__ partL,
    float* __restrict__ attn)
{
  const int bid = blockIdx.x;             // ((b*32 + h)*4 + s)
  const int s = bid & 3;
  const int h = (bid >> 2) & 31;
  const int b = bid >> 7;
  const int kv = h >> 2;
  const int lane = threadIdx.x;
  const int d0 = lane * 2;

  float M = -INFINITY;
  #pragma unroll 4
  for (int c = 0; c < NCH; ++c) M = fmaxf(M, partM[bid * NCH + c]);

  float qr0, qr1;
  {
    const float* qp = qraw + (size_t)(b * 4 + s) * HIDK + h * HD;
    const float c0 = cosp[(b * 4 + s) * HD + d0],     sn0 = sinp[(b * 4 + s) * HD + d0];
    const float c1 = cosp[(b * 4 + s) * HD + d0 + 1], sn1 = sinp[(b * 4 + s) * HD + d0 + 1];
    const float sg0 = (d0 < 64) ? -1.f : 1.f;
    const float sg1 = ((d0 + 1) < 64) ? -1.f : 1.f;
    qr0 = (qp[d0] * c0 + sg0 * qp[d0 ^ 64] * sn0) * SCALE;
    qr1 = (qp[d0 + 1] * c1 + sg1 * qp[(d0 + 1) ^ 64] * sn1) * SCALE;
  }

  float sj[4] = {0.f, 0.f, 0.f, 0.f};
  float Mp = M;
  #pragma unroll
  for (int j = 0; j < 4; ++j) {
    if (j <= s) {
      const float* kp = kraw + (size_t)(b * 4 + j) * 1024 + kv * HD;
      const float c0 = cosp[(b * 4 + j) * HD + d0],     sn0 = sinp[(b * 4 + j) * HD + d0];
      const float c1 = cosp[(b * 4 + j) * HD + d0 + 1], sn1 = sinp[(b * 4 + j) * HD + d0 + 1];
      const float sg0 = (d0 < 64) ? -1.f : 1.f;
      const float sg1 = ((d0 + 1) < 64) ? -1.f : 1.f;
      const float kr0 = kp[d0] * c0 + sg0 * kp[d0 ^ 64] * sn0;
      const float kr1 = kp[d0 + 1] * c1 + sg1 * kp[(d0 + 1) ^ 64] * sn1;
      float part = qr0 * kr0 + qr1 * kr1;
      #pragma unroll
      for (int m = 1; m < 64; m <<= 1) part += __shfl_xor(part, m, 64);
      sj[j] = part;
      Mp = fmaxf(Mp, part);
    }
  }

  float ltot = 0.f, O0 = 0.f, O1 = 0.f;
  #pragma unroll 4
  for (int c = 0; c < NCH; ++c) {
    const float a = __expf(partM[bid * NCH + c] - Mp);
    ltot += partL[bid * NCH + c] * a;
    const float2 v = *(const float2*)&partO[((size_t)bid * NCH + c) * HD + d0];
    O0 += a * v.x;
    O1 += a * v.y;
  }
  #pragma unroll
  for (int j = 0; j < 4; ++j) {
    if (j <= s) {
      const float e = __expf(sj[j] - Mp);
      ltot += e;
      const float* vp = vraw + (size_t)(b * 4 + j) * 1024 + kv * HD + d0;
      O0 += e * vp[0];
      O1 += e * vp[1];
    }
  }
  const float inv = 1.f / ltot;
  *(float2*)&attn[(size_t)(b * 4 + s) * HIDK + h * HD + d0] = make_float2(O0 * inv, O1 * inv);
}

// ---------------------------------------------------------------------------
extern "C" void kernel_launch(void* const* d_in, const int* in_sizes, int n_in,
                              void* d_out, int out_size, void* d_ws, size_t ws_size,
                              hipStream_t stream)
{
  const float* hid  = (const float*)d_in[0];
  const float* cosp = (const float*)d_in[1];
  const float* sinp = (const float*)d_in[2];
  const float* Kc   = (const float*)d_in[3];
  const float* Vc   = (const float*)d_in[4];
  const float* Wq   = (const float*)d_in[5];
  const float* Wk   = (const float*)d_in[6];
  const float* Wv   = (const float*)d_in[7];
  const float* Wo   = (const float*)d_in[8];
  float* out = (float*)d_out;

  float* ws    = (float*)d_ws;
  float* qraw  = ws;                 // 16*4096  = 65536
  float* kraw  = ws + 65536;         // 16*1024  = 16384
  float* vraw  = ws + 81920;         // 16*1024  = 16384
  float* attn  = ws + 98304;         // 16*4096  = 65536
  float* partO = ws + 163840;        // 512*32*128 = 2097152
  float* partM = partO + (size_t)512 * NCH * 128;   // 16384
  float* partL = partM + (size_t)512 * NCH;          // 16384  (total 9.18 MB, proven fits)

  // A: QKV projection (raw, un-roped): 6144 outputs, 8 per block
  gemm3_kernel<<<768, 256, 0, stream>>>(hid, Wq, Wk, Wv, 4096, 1024,
                                        qraw, 4096, kraw, 1024, vraw, 1024);
  // B: attention over the 4096 cached positions, 32 chunks of 128
  attn2_kernel<<<32 * NCH, 256, 0, stream>>>(qraw, Kc, Vc, cosp, sinp, partO, partM, partL);
  // C: combine + new causal tokens
  combine_kernel<<<512, 64, 0, stream>>>(qraw, kraw, vraw, cosp, sinp, partO, partM, partL, attn);
  // D: output projection: 4096 outputs
  gemm3_kernel<<<512, 256, 0, stream>>>(attn, Wo, Wo, Wo, 4096, 0,
                                        out, 4096, out, 4096, out, 4096);
}

// Round 5
// 121.357 us; speedup vs baseline: 2.7072x; 1.1232x over previous
//
#include <hip/hip_runtime.h>
#include <hip/hip_fp16.h>
#include <math.h>

#define HIDK 4096
#define NHQ 32
#define HD 128
#define CMAX 4608
#define CLEN 4096
#define NCH 32          // 128-position chunks (2 x 64-pos waves per block)
#define SCALE 0.08838834764831845f   // 1/sqrt(128)

__device__ __forceinline__ float4 ld4(const float* p) { return *reinterpret_cast<const float4*>(p); }
__device__ __forceinline__ float dot4(float4 a, float4 b) { return a.x*b.x + a.y*b.y + a.z*b.z + a.w*b.w; }

// ---------------------------------------------------------------------------
// GEMM: out[bs,o] = sum_k X[bs,k]*W[o,k]  (M=16, K=4096), 4 waves/block,
// 2 outputs/wave, X double-buffered through LDS. (unchanged from R4)
// ---------------------------------------------------------------------------
__global__ __launch_bounds__(256) void gemm3_kernel(
    const float* __restrict__ X,
    const float* __restrict__ W1, const float* __restrict__ W2, const float* __restrict__ W3,
    int n1, int n2,
    float* __restrict__ o1, int os1,
    float* __restrict__ o2, int os2,
    float* __restrict__ o3, int os3)
{
  __shared__ float Xs[2][16][256];

  const int tid = threadIdx.x, lane = tid & 63, w = tid >> 6;
  const int o = blockIdx.x * 8 + w * 2;

  const float* Wb; float* ob; int os;
  if (o < n1)           { Wb = W1 + (size_t)o * HIDK;            ob = o1 + o;            os = os1; }
  else if (o < n1 + n2) { const int f = o - n1;      Wb = W2 + (size_t)f * HIDK; ob = o2 + f; os = os2; }
  else                  { const int f = o - n1 - n2; Wb = W3 + (size_t)f * HIDK; ob = o3 + f; os = os3; }

  const int strow = tid >> 6;
  const int stcol = (tid & 63) * 4;

  float acc0[16], acc1[16];
  #pragma unroll
  for (int b = 0; b < 16; ++b) { acc0[b] = 0.f; acc1[b] = 0.f; }

  #pragma unroll
  for (int j = 0; j < 4; ++j)
    *(float4*)&Xs[0][strow + j * 4][stcol] = ld4(X + (size_t)(strow + j * 4) * HIDK + stcol);

  int cur = 0;
  #pragma unroll 2
  for (int kt = 0; kt < 16; ++kt) {
    const float4 w0 = ld4(Wb + (size_t)kt * 256 + lane * 4);
    const float4 w1 = ld4(Wb + HIDK + (size_t)kt * 256 + lane * 4);
    float4 g[4];
    if (kt < 15) {
      #pragma unroll
      for (int j = 0; j < 4; ++j)
        g[j] = ld4(X + (size_t)(strow + j * 4) * HIDK + (kt + 1) * 256 + stcol);
    }
    __syncthreads();
    #pragma unroll
    for (int b = 0; b < 16; ++b) {
      const float4 x4 = *(const float4*)&Xs[cur][b][lane * 4];
      acc0[b] += dot4(x4, w0);
      acc1[b] += dot4(x4, w1);
    }
    if (kt < 15) {
      #pragma unroll
      for (int j = 0; j < 4; ++j)
        *(float4*)&Xs[cur ^ 1][strow + j * 4][stcol] = g[j];
    }
    cur ^= 1;
  }

  #pragma unroll
  for (int m = 1; m < 64; m <<= 1)
    #pragma unroll
    for (int b = 0; b < 16; ++b) {
      acc0[b] += __shfl_xor(acc0[b], m, 64);
      acc1[b] += __shfl_xor(acc1[b], m, 64);
    }
  if (lane == 0) {
    #pragma unroll
    for (int b = 0; b < 16; ++b) {
      ob[(size_t)b * os]     = acc0[b];
      ob[(size_t)b * os + 1] = acc1[b];
    }
  }
}

// ---------------------------------------------------------------------------
// Q prep: RoPE * SCALE, transposed to qt[(bkv*128 + d)*16 + (hl*4+s)]
// so the attention score loop can read Q via wave-uniform scalar loads.
// ---------------------------------------------------------------------------
__global__ __launch_bounds__(256) void qt_prep_kernel(
    const float* __restrict__ qraw, const float* __restrict__ cosp,
    const float* __restrict__ sinp, float* __restrict__ qt)
{
  const int e = blockIdx.x * 256 + threadIdx.x;   // 65536 total
  const int r = e & 15;            // hl*4 + s
  const int d = (e >> 4) & 127;
  const int bkv = e >> 11;         // 0..31
  const int b = bkv >> 3, kv = bkv & 7;
  const int s = r & 3, hl = r >> 2;
  const float* qp = qraw + (size_t)(b * 4 + s) * HIDK + (kv * 4 + hl) * HD;
  const float c  = cosp[(b * 4 + s) * HD + d];
  const float sn = sinp[(b * 4 + s) * HD + d];
  const float sgn = (d < 64) ? -1.f : 1.f;
  qt[e] = (qp[d] * c + sgn * qp[d ^ 64] * sn) * SCALE;
}

// ---------------------------------------------------------------------------
// Attention: 1024 blocks x 128 thr (2 independent waves). Block = (b,kv) x
// 128-pos chunk; wave w owns 64 positions. lane=position for scores (Q via
// uniform s_load, K streamed per-lane), P through 4KB per-wave LDS, V
// streamed coalesced. One barrier: in-block flash-combine -> fp16 partials.
// ---------------------------------------------------------------------------
__global__ __launch_bounds__(128) void attn3_kernel(
    const float* __restrict__ qt, const float* __restrict__ Kc, const float* __restrict__ Vc,
    __half* __restrict__ partOh, float* __restrict__ partM, float* __restrict__ partL)
{
  __shared__ float Plds[2][16][66];   // per-wave P transpose
  __shared__ float Oex[16][132];      // wave1 -> wave0 O exchange
  __shared__ float MLe[32];           // wave1 m[16], l[16]

  const int tid = threadIdx.x, lane = tid & 63, w = tid >> 6;
  const int chunk = blockIdx.x & 31, bkv = blockIdx.x >> 5;
  const int b = bkv >> 3, kv = bkv & 7;
  const int p0 = chunk * 128 + w * 64;

  const float* qtb = qt + (size_t)bkv * 2048;            // [d][16 rows]
  const float* Kp  = Kc + ((size_t)bkv * CMAX + p0 + lane) * HD;

  // ---- scores: lane = position, fully lane-local dot ----
  float sc[16];
  #pragma unroll
  for (int r = 0; r < 16; ++r) sc[r] = 0.f;
  #pragma unroll 4
  for (int d4 = 0; d4 < 32; ++d4) {
    const float4 k4 = ld4(Kp + d4 * 4);
    #pragma unroll
    for (int r = 0; r < 16; ++r) sc[r] += k4.x * qtb[(d4 * 4 + 0) * 16 + r];
    #pragma unroll
    for (int r = 0; r < 16; ++r) sc[r] += k4.y * qtb[(d4 * 4 + 1) * 16 + r];
    #pragma unroll
    for (int r = 0; r < 16; ++r) sc[r] += k4.z * qtb[(d4 * 4 + 2) * 16 + r];
    #pragma unroll
    for (int r = 0; r < 16; ++r) sc[r] += k4.w * qtb[(d4 * 4 + 3) * 16 + r];
  }

  // ---- softmax across the wave's 64 positions (once) ----
  float m[16], l[16];
  #pragma unroll
  for (int r = 0; r < 16; ++r) {
    float mx = sc[r];
    #pragma unroll
    for (int st = 1; st < 64; st <<= 1) mx = fmaxf(mx, __shfl_xor(mx, st, 64));
    const float p = __expf(sc[r] - mx);
    float ls = p;
    #pragma unroll
    for (int st = 1; st < 64; st <<= 1) ls += __shfl_xor(ls, st, 64);
    m[r] = mx; l[r] = ls;
    Plds[w][r][lane] = p;
  }

  // ---- PV: lane = (dim-quad, pos-parity), V coalesced from global ----
  const int dsub = lane & 31, par = lane >> 5;
  const float* Vp = Vc + ((size_t)bkv * CMAX + p0 + par) * HD + dsub * 4;
  float4 o[16];
  #pragma unroll
  for (int r = 0; r < 16; ++r) o[r] = make_float4(0.f, 0.f, 0.f, 0.f);
  #pragma unroll 4
  for (int i = 0; i < 32; ++i) {
    const float4 v4 = ld4(Vp + (size_t)(2 * i) * HD);    // pos = p0 + 2i + par
    #pragma unroll
    for (int r = 0; r < 16; ++r) {
      const float p = Plds[w][r][2 * i + par];
      o[r].x += p * v4.x; o[r].y += p * v4.y; o[r].z += p * v4.z; o[r].w += p * v4.w;
    }
  }
  #pragma unroll
  for (int r = 0; r < 16; ++r) {
    o[r].x += __shfl_xor(o[r].x, 32, 64);
    o[r].y += __shfl_xor(o[r].y, 32, 64);
    o[r].z += __shfl_xor(o[r].z, 32, 64);
    o[r].w += __shfl_xor(o[r].w, 32, 64);
  }

  // ---- in-block flash-combine of the two 64-pos halves ----
  if (w == 1) {
    if (lane < 32) {
      #pragma unroll
      for (int r = 0; r < 16; ++r) *(float4*)&Oex[r][dsub * 4] = o[r];
    }
    if (lane == 0) {
      #pragma unroll
      for (int r = 0; r < 16; ++r) { MLe[r] = m[r]; MLe[16 + r] = l[r]; }
    }
  }
  __syncthreads();
  if (w == 0 && lane < 32) {
    #pragma unroll
    for (int r = 0; r < 16; ++r) {
      const float m1 = MLe[r], l1 = MLe[16 + r];
      const float M  = fmaxf(m[r], m1);
      const float a0 = __expf(m[r] - M), a1 = __expf(m1 - M);
      const float4 o1 = *(const float4*)&Oex[r][dsub * 4];
      const float ox = a0 * o[r].x + a1 * o1.x;
      const float oy = a0 * o[r].y + a1 * o1.y;
      const float oz = a0 * o[r].z + a1 * o1.z;
      const float ow = a0 * o[r].w + a1 * o1.w;
      const int row = (b * NHQ + kv * 4 + (r >> 2)) * 4 + (r & 3);
      const size_t idx = ((size_t)row * NCH + chunk) * HD + dsub * 4;
      *(__half2*)&partOh[idx]     = __floats2half2_rn(ox, oy);
      *(__half2*)&partOh[idx + 2] = __floats2half2_rn(oz, ow);
      if (dsub == 0) {
        partM[row * NCH + chunk] = M;
        partL[row * NCH + chunk] = a0 * l[r] + a1 * l1;
      }
    }
  }
}

// ---------------------------------------------------------------------------
// Flash-combine 32 chunk partials (fp16) + <=4 new causal tokens. 512 x 64.
// ---------------------------------------------------------------------------
__global__ __launch_bounds__(64) void combine_kernel(
    const float* __restrict__ qt, const float* __restrict__ kraw, const float* __restrict__ vraw,
    const float* __restrict__ cosp, const float* __restrict__ sinp,
    const __half* __restrict__ partOh, const float* __restrict__ partM, const float* __restrict__ partL,
    float* __restrict__ attn)
{
  const int bid = blockIdx.x;             // ((b*32 + h)*4 + s)
  const int s = bid & 3;
  const int h = (bid >> 2) & 31;
  const int b = bid >> 7;
  const int kv = h >> 2;
  const int lane = threadIdx.x;
  const int d0 = lane * 2;

  float M = -INFINITY;
  #pragma unroll 4
  for (int c = 0; c < NCH; ++c) M = fmaxf(M, partM[bid * NCH + c]);

  // roped, scaled q from qt
  const int rloc = (h & 3) * 4 + s;
  const float qr0 = qt[((size_t)(b * 8 + kv) * 128 + d0) * 16 + rloc];
  const float qr1 = qt[((size_t)(b * 8 + kv) * 128 + d0 + 1) * 16 + rloc];

  float sj[4] = {0.f, 0.f, 0.f, 0.f};
  float Mp = M;
  #pragma unroll
  for (int j = 0; j < 4; ++j) {
    if (j <= s) {
      const float* kp = kraw + (size_t)(b * 4 + j) * 1024 + kv * HD;
      const float c0 = cosp[(b * 4 + j) * HD + d0],     sn0 = sinp[(b * 4 + j) * HD + d0];
      const float c1 = cosp[(b * 4 + j) * HD + d0 + 1], sn1 = sinp[(b * 4 + j) * HD + d0 + 1];
      const float sg0 = (d0 < 64) ? -1.f : 1.f;
      const float sg1 = ((d0 + 1) < 64) ? -1.f : 1.f;
      const float kr0 = kp[d0] * c0 + sg0 * kp[d0 ^ 64] * sn0;
      const float kr1 = kp[d0 + 1] * c1 + sg1 * kp[(d0 + 1) ^ 64] * sn1;
      float part = qr0 * kr0 + qr1 * kr1;
      #pragma unroll
      for (int m = 1; m < 64; m <<= 1) part += __shfl_xor(part, m, 64);
      sj[j] = part;
      Mp = fmaxf(Mp, part);
    }
  }

  float ltot = 0.f, O0 = 0.f, O1 = 0.f;
  #pragma unroll 4
  for (int c = 0; c < NCH; ++c) {
    const float a = __expf(partM[bid * NCH + c] - Mp);
    ltot += partL[bid * NCH + c] * a;
    const float2 v = __half22float2(*(const __half2*)&partOh[((size_t)bid * NCH + c) * HD + d0]);
    O0 += a * v.x;
    O1 += a * v.y;
  }
  #pragma unroll
  for (int j = 0; j < 4; ++j) {
    if (j <= s) {
      const float e = __expf(sj[j] - Mp);
      ltot += e;
      const float* vp = vraw + (size_t)(b * 4 + j) * 1024 + kv * HD + d0;
      O0 += e * vp[0];
      O1 += e * vp[1];
    }
  }
  const float inv = 1.f / ltot;
  *(float2*)&attn[(size_t)(b * 4 + s) * HIDK + h * HD + d0] = make_float2(O0 * inv, O1 * inv);
}

// ---------------------------------------------------------------------------
extern "C" void kernel_launch(void* const* d_in, const int* in_sizes, int n_in,
                              void* d_out, int out_size, void* d_ws, size_t ws_size,
                              hipStream_t stream)
{
  const float* hid  = (const float*)d_in[0];
  const float* cosp = (const float*)d_in[1];
  const float* sinp = (const float*)d_in[2];
  const float* Kc   = (const float*)d_in[3];
  const float* Vc   = (const float*)d_in[4];
  const float* Wq   = (const float*)d_in[5];
  const float* Wk   = (const float*)d_in[6];
  const float* Wv   = (const float*)d_in[7];
  const float* Wo   = (const float*)d_in[8];
  float* out = (float*)d_out;

  float* ws    = (float*)d_ws;
  float*  kraw   = ws;                      // 16384
  float*  vraw   = ws + 16384;              // 16384
  float*  attn   = ws + 32768;              // 65536
  float*  qt     = ws + 98304;              // 65536
  float*  qraw   = ws + 163840;             // 65536
  float*  partM  = ws + 229376;             // 512*32 = 16384
  float*  partL  = ws + 245760;             // 16384
  __half* partOh = (__half*)(ws + 262144);  // 512*32*128 halves = 1048576 floats
  // total 1,310,720 floats = 5.24 MB (< proven 9.18 MB)

  // A: QKV projection (raw, un-roped)
  gemm3_kernel<<<768, 256, 0, stream>>>(hid, Wq, Wk, Wv, 4096, 1024,
                                        qraw, 4096, kraw, 1024, vraw, 1024);
  // A': RoPE + scale + transpose q
  qt_prep_kernel<<<256, 256, 0, stream>>>(qraw, cosp, sinp, qt);
  // B: attention over the 4096 cached positions
  attn3_kernel<<<1024, 128, 0, stream>>>(qt, Kc, Vc, partOh, partM, partL);
  // C: combine + new causal tokens
  combine_kernel<<<512, 64, 0, stream>>>(qt, kraw, vraw, cosp, sinp,
                                         partOh, partM, partL, attn);
  // D: output projection
  gemm3_kernel<<<512, 256, 0, stream>>>(attn, Wo, Wo, Wo, 4096, 0,
                                        out, 4096, out, 4096, out, 4096);
}

// Round 6
// 111.314 us; speedup vs baseline: 2.9514x; 1.0902x over previous
//
#include <hip/hip_runtime.h>
#include <hip/hip_fp16.h>
#include <math.h>

#define HIDK 4096
#define NHQ 32
#define HD 128
#define CMAX 4608
#define CLEN 4096
#define NCH 32          // 128-position chunks (2 x 64-pos waves per block)
#define SCALE 0.08838834764831845f   // 1/sqrt(128)

__device__ __forceinline__ float4 ld4(const float* p) { return *reinterpret_cast<const float4*>(p); }
__device__ __forceinline__ float dot4(float4 a, float4 b) { return a.x*b.x + a.y*b.y + a.z*b.z + a.w*b.w; }

// ---------------------------------------------------------------------------
// GEMM: out[bs,o] = sum_k X[bs,k]*W[o,k]  (M=16, K=4096), 4 waves/block,
// 2 outputs/wave, X double-buffered through LDS. (unchanged)
// ---------------------------------------------------------------------------
__global__ __launch_bounds__(256) void gemm3_kernel(
    const float* __restrict__ X,
    const float* __restrict__ W1, const float* __restrict__ W2, const float* __restrict__ W3,
    int n1, int n2,
    float* __restrict__ o1, int os1,
    float* __restrict__ o2, int os2,
    float* __restrict__ o3, int os3)
{
  __shared__ float Xs[2][16][256];

  const int tid = threadIdx.x, lane = tid & 63, w = tid >> 6;
  const int o = blockIdx.x * 8 + w * 2;

  const float* Wb; float* ob; int os;
  if (o < n1)           { Wb = W1 + (size_t)o * HIDK;            ob = o1 + o;            os = os1; }
  else if (o < n1 + n2) { const int f = o - n1;      Wb = W2 + (size_t)f * HIDK; ob = o2 + f; os = os2; }
  else                  { const int f = o - n1 - n2; Wb = W3 + (size_t)f * HIDK; ob = o3 + f; os = os3; }

  const int strow = tid >> 6;
  const int stcol = (tid & 63) * 4;

  float acc0[16], acc1[16];
  #pragma unroll
  for (int b = 0; b < 16; ++b) { acc0[b] = 0.f; acc1[b] = 0.f; }

  #pragma unroll
  for (int j = 0; j < 4; ++j)
    *(float4*)&Xs[0][strow + j * 4][stcol] = ld4(X + (size_t)(strow + j * 4) * HIDK + stcol);

  int cur = 0;
  #pragma unroll 2
  for (int kt = 0; kt < 16; ++kt) {
    const float4 w0 = ld4(Wb + (size_t)kt * 256 + lane * 4);
    const float4 w1 = ld4(Wb + HIDK + (size_t)kt * 256 + lane * 4);
    float4 g[4];
    if (kt < 15) {
      #pragma unroll
      for (int j = 0; j < 4; ++j)
        g[j] = ld4(X + (size_t)(strow + j * 4) * HIDK + (kt + 1) * 256 + stcol);
    }
    __syncthreads();
    #pragma unroll
    for (int b = 0; b < 16; ++b) {
      const float4 x4 = *(const float4*)&Xs[cur][b][lane * 4];
      acc0[b] += dot4(x4, w0);
      acc1[b] += dot4(x4, w1);
    }
    if (kt < 15) {
      #pragma unroll
      for (int j = 0; j < 4; ++j)
        *(float4*)&Xs[cur ^ 1][strow + j * 4][stcol] = g[j];
    }
    cur ^= 1;
  }

  #pragma unroll
  for (int m = 1; m < 64; m <<= 1)
    #pragma unroll
    for (int b = 0; b < 16; ++b) {
      acc0[b] += __shfl_xor(acc0[b], m, 64);
      acc1[b] += __shfl_xor(acc1[b], m, 64);
    }
  if (lane == 0) {
    #pragma unroll
    for (int b = 0; b < 16; ++b) {
      ob[(size_t)b * os]     = acc0[b];
      ob[(size_t)b * os + 1] = acc1[b];
    }
  }
}

// ---------------------------------------------------------------------------
// Q prep: RoPE * SCALE -> qt[bkv][r][d]  (r = hl*4+s, d = 0..127)
// ---------------------------------------------------------------------------
__global__ __launch_bounds__(256) void qt_prep_kernel(
    const float* __restrict__ qraw, const float* __restrict__ cosp,
    const float* __restrict__ sinp, float* __restrict__ qt)
{
  const int e = blockIdx.x * 256 + threadIdx.x;   // 65536 total
  const int d = e & 127;
  const int r = (e >> 7) & 15;     // hl*4 + s
  const int bkv = e >> 11;         // 0..31
  const int b = bkv >> 3, kv = bkv & 7;
  const int s = r & 3, hl = r >> 2;
  const float* qp = qraw + (size_t)(b * 4 + s) * HIDK + (kv * 4 + hl) * HD;
  const float c  = cosp[(b * 4 + s) * HD + d];
  const float sn = sinp[(b * 4 + s) * HD + d];
  const float sgn = (d < 64) ? -1.f : 1.f;
  qt[e] = (qp[d] * c + sgn * qp[d ^ 64] * sn) * SCALE;
}

// ---------------------------------------------------------------------------
// Attention: 1024 blocks x 128 thr (2 indep waves). Wave owns 64 positions,
// lane = position. Q from LDS (lgkmcnt), K streamed 8-deep (vmcnt only),
// V streamed 4-deep through softmax, P read as b128 row-quads.
// ---------------------------------------------------------------------------
__global__ __launch_bounds__(128) void attn4_kernel(
    const float* __restrict__ qt, const float* __restrict__ Kc, const float* __restrict__ Vc,
    __half* __restrict__ partOh, float* __restrict__ partM, float* __restrict__ partL)
{
  __shared__ float qsh[16][128];      // 8KB, shared by both waves
  __shared__ float P[2][64][20];      // per-wave [pos][row], pad 20
  __shared__ float Oex[16][132];      // wave1 -> wave0 O exchange
  __shared__ float MLe[32];

  const int tid = threadIdx.x, lane = tid & 63, w = tid >> 6;
  const int chunk = blockIdx.x & 31, bkv = blockIdx.x >> 5;
  const int b = bkv >> 3, kv = bkv & 7;
  const int p0 = chunk * 128 + w * 64;

  // stage Q (2048 floats, both waves help)
  #pragma unroll
  for (int j = 0; j < 4; ++j) {
    const int fi = (tid + j * 128) * 4;
    *(float4*)&qsh[0][fi] = ld4(qt + (size_t)bkv * 2048 + fi);
  }
  __syncthreads();

  // ---- scores: lane = position, K 8-deep prefetch, Q via LDS broadcast ----
  const float* Kp = Kc + ((size_t)bkv * CMAX + p0 + lane) * HD;
  float sc[16];
  #pragma unroll
  for (int r = 0; r < 16; ++r) sc[r] = 0.f;

  float4 kbuf[8];
  #pragma unroll
  for (int i = 0; i < 8; ++i) kbuf[i] = ld4(Kp + i * 4);

  #pragma unroll
  for (int sb = 0; sb < 4; ++sb) {
    float4 kn[8];
    if (sb < 3) {
      #pragma unroll
      for (int i = 0; i < 8; ++i) kn[i] = ld4(Kp + ((sb + 1) * 8 + i) * 4);
    }
    #pragma unroll
    for (int i = 0; i < 8; ++i) {
      const int d4 = sb * 8 + i;
      const float4 k4 = kbuf[i];
      #pragma unroll
      for (int r = 0; r < 16; ++r)
        sc[r] += dot4(k4, *(const float4*)&qsh[r][d4 * 4]);
    }
    if (sb < 3) {
      #pragma unroll
      for (int i = 0; i < 8; ++i) kbuf[i] = kn[i];
    }
  }

  // ---- prefetch V 4-deep before softmax ----
  const int dsub = lane & 31, par = lane >> 5;
  const float* Vp = Vc + ((size_t)bkv * CMAX + p0 + par) * HD + dsub * 4;
  float4 vbuf[4];
  #pragma unroll
  for (int i = 0; i < 4; ++i) vbuf[i] = ld4(Vp + (size_t)(2 * i) * HD);

  // ---- softmax across the wave's 64 positions ----
  float m[16], l[16];
  #pragma unroll
  for (int r = 0; r < 16; ++r) {
    float mx = sc[r];
    #pragma unroll
    for (int st = 1; st < 64; st <<= 1) mx = fmaxf(mx, __shfl_xor(mx, st, 64));
    const float p = __expf(sc[r] - mx);
    float ls = p;
    #pragma unroll
    for (int st = 1; st < 64; st <<= 1) ls += __shfl_xor(ls, st, 64);
    m[r] = mx; l[r] = ls;
    P[w][lane][r] = p;
  }

  // ---- PV: lane = (dim-quad, pos-parity), V 4-deep, P as b128 row-quads ----
  float4 o[16];
  #pragma unroll
  for (int r = 0; r < 16; ++r) o[r] = make_float4(0.f, 0.f, 0.f, 0.f);

  #pragma unroll
  for (int sb = 0; sb < 8; ++sb) {
    float4 vn[4];
    if (sb < 7) {
      #pragma unroll
      for (int i = 0; i < 4; ++i) vn[i] = ld4(Vp + (size_t)(2 * ((sb + 1) * 4 + i)) * HD);
    }
    #pragma unroll
    for (int i = 0; i < 4; ++i) {
      const int pc = 2 * (sb * 4 + i) + par;
      const float4 v4 = vbuf[i];
      #pragma unroll
      for (int rq = 0; rq < 4; ++rq) {
        const float4 p4 = *(const float4*)&P[w][pc][rq * 4];
        o[rq*4+0].x += p4.x * v4.x; o[rq*4+0].y += p4.x * v4.y; o[rq*4+0].z += p4.x * v4.z; o[rq*4+0].w += p4.x * v4.w;
        o[rq*4+1].x += p4.y * v4.x; o[rq*4+1].y += p4.y * v4.y; o[rq*4+1].z += p4.y * v4.z; o[rq*4+1].w += p4.y * v4.w;
        o[rq*4+2].x += p4.z * v4.x; o[rq*4+2].y += p4.z * v4.y; o[rq*4+2].z += p4.z * v4.z; o[rq*4+2].w += p4.z * v4.w;
        o[rq*4+3].x += p4.w * v4.x; o[rq*4+3].y += p4.w * v4.y; o[rq*4+3].z += p4.w * v4.z; o[rq*4+3].w += p4.w * v4.w;
      }
    }
    if (sb < 7) {
      #pragma unroll
      for (int i = 0; i < 4; ++i) vbuf[i] = vn[i];
    }
  }
  #pragma unroll
  for (int r = 0; r < 16; ++r) {
    o[r].x += __shfl_xor(o[r].x, 32, 64);
    o[r].y += __shfl_xor(o[r].y, 32, 64);
    o[r].z += __shfl_xor(o[r].z, 32, 64);
    o[r].w += __shfl_xor(o[r].w, 32, 64);
  }

  // ---- in-block flash-combine of the two 64-pos halves ----
  if (w == 1) {
    if (lane < 32) {
      #pragma unroll
      for (int r = 0; r < 16; ++r) *(float4*)&Oex[r][dsub * 4] = o[r];
    }
    if (lane == 0) {
      #pragma unroll
      for (int r = 0; r < 16; ++r) { MLe[r] = m[r]; MLe[16 + r] = l[r]; }
    }
  }
  __syncthreads();
  if (w == 0 && lane < 32) {
    #pragma unroll
    for (int r = 0; r < 16; ++r) {
      const float m1 = MLe[r], l1 = MLe[16 + r];
      const float M  = fmaxf(m[r], m1);
      const float a0 = __expf(m[r] - M), a1 = __expf(m1 - M);
      const float4 o1 = *(const float4*)&Oex[r][dsub * 4];
      const float ox = a0 * o[r].x + a1 * o1.x;
      const float oy = a0 * o[r].y + a1 * o1.y;
      const float oz = a0 * o[r].z + a1 * o1.z;
      const float ow = a0 * o[r].w + a1 * o1.w;
      const int row = (b * NHQ + kv * 4 + (r >> 2)) * 4 + (r & 3);
      const size_t idx = ((size_t)row * NCH + chunk) * HD + dsub * 4;
      *(__half2*)&partOh[idx]     = __floats2half2_rn(ox, oy);
      *(__half2*)&partOh[idx + 2] = __floats2half2_rn(oz, ow);
      if (dsub == 0) {
        partM[row * NCH + chunk] = M;
        partL[row * NCH + chunk] = a0 * l[r] + a1 * l1;
      }
    }
  }
}

// ---------------------------------------------------------------------------
// Flash-combine 32 chunk partials (fp16) + <=4 new causal tokens. 512 x 64.
// ---------------------------------------------------------------------------
__global__ __launch_bounds__(64) void combine_kernel(
    const float* __restrict__ qt, const float* __restrict__ kraw, const float* __restrict__ vraw,
    const float* __restrict__ cosp, const float* __restrict__ sinp,
    const __half* __restrict__ partOh, const float* __restrict__ partM, const float* __restrict__ partL,
    float* __restrict__ attn)
{
  const int bid = blockIdx.x;             // ((b*32 + h)*4 + s)
  const int s = bid & 3;
  const int h = (bid >> 2) & 31;
  const int b = bid >> 7;
  const int kv = h >> 2;
  const int lane = threadIdx.x;
  const int d0 = lane * 2;

  float M = -INFINITY;
  #pragma unroll 4
  for (int c = 0; c < NCH; ++c) M = fmaxf(M, partM[bid * NCH + c]);

  // roped, scaled q from qt[bkv][r][d]
  const int rloc = (h & 3) * 4 + s;
  const float qr0 = qt[((size_t)(b * 8 + kv) * 16 + rloc) * 128 + d0];
  const float qr1 = qt[((size_t)(b * 8 + kv) * 16 + rloc) * 128 + d0 + 1];

  float sj[4] = {0.f, 0.f, 0.f, 0.f};
  float Mp = M;
  #pragma unroll
  for (int j = 0; j < 4; ++j) {
    if (j <= s) {
      const float* kp = kraw + (size_t)(b * 4 + j) * 1024 + kv * HD;
      const float c0 = cosp[(b * 4 + j) * HD + d0],     sn0 = sinp[(b * 4 + j) * HD + d0];
      const float c1 = cosp[(b * 4 + j) * HD + d0 + 1], sn1 = sinp[(b * 4 + j) * HD + d0 + 1];
      const float sg0 = (d0 < 64) ? -1.f : 1.f;
      const float sg1 = ((d0 + 1) < 64) ? -1.f : 1.f;
      const float kr0 = kp[d0] * c0 + sg0 * kp[d0 ^ 64] * sn0;
      const float kr1 = kp[d0 + 1] * c1 + sg1 * kp[(d0 + 1) ^ 64] * sn1;
      float part = qr0 * kr0 + qr1 * kr1;
      #pragma unroll
      for (int m = 1; m < 64; m <<= 1) part += __shfl_xor(part, m, 64);
      sj[j] = part;
      Mp = fmaxf(Mp, part);
    }
  }

  float ltot = 0.f, O0 = 0.f, O1 = 0.f;
  #pragma unroll 4
  for (int c = 0; c < NCH; ++c) {
    const float a = __expf(partM[bid * NCH + c] - Mp);
    ltot += partL[bid * NCH + c] * a;
    const float2 v = __half22float2(*(const __half2*)&partOh[((size_t)bid * NCH + c) * HD + d0]);
    O0 += a * v.x;
    O1 += a * v.y;
  }
  #pragma unroll
  for (int j = 0; j < 4; ++j) {
    if (j <= s) {
      const float e = __expf(sj[j] - Mp);
      ltot += e;
      const float* vp = vraw + (size_t)(b * 4 + j) * 1024 + kv * HD + d0;
      O0 += e * vp[0];
      O1 += e * vp[1];
    }
  }
  const float inv = 1.f / ltot;
  *(float2*)&attn[(size_t)(b * 4 + s) * HIDK + h * HD + d0] = make_float2(O0 * inv, O1 * inv);
}

// ---------------------------------------------------------------------------
extern "C" void kernel_launch(void* const* d_in, const int* in_sizes, int n_in,
                              void* d_out, int out_size, void* d_ws, size_t ws_size,
                              hipStream_t stream)
{
  const float* hid  = (const float*)d_in[0];
  const float* cosp = (const float*)d_in[1];
  const float* sinp = (const float*)d_in[2];
  const float* Kc   = (const float*)d_in[3];
  const float* Vc   = (const float*)d_in[4];
  const float* Wq   = (const float*)d_in[5];
  const float* Wk   = (const float*)d_in[6];
  const float* Wv   = (const float*)d_in[7];
  const float* Wo   = (const float*)d_in[8];
  float* out = (float*)d_out;

  float* ws    = (float*)d_ws;
  float*  kraw   = ws;                      // 16384
  float*  vraw   = ws + 16384;              // 16384
  float*  attn   = ws + 32768;              // 65536
  float*  qt     = ws + 98304;              // 65536
  float*  qraw   = ws + 163840;             // 65536
  float*  partM  = ws + 229376;             // 512*32 = 16384
  float*  partL  = ws + 245760;             // 16384
  __half* partOh = (__half*)(ws + 262144);  // 512*32*128 halves = 1048576 floats
  // total 1,310,720 floats = 5.24 MB

  // A: QKV projection (raw, un-roped)
  gemm3_kernel<<<768, 256, 0, stream>>>(hid, Wq, Wk, Wv, 4096, 1024,
                                        qraw, 4096, kraw, 1024, vraw, 1024);
  // A': RoPE + scale q -> qt[bkv][r][d]
  qt_prep_kernel<<<256, 256, 0, stream>>>(qraw, cosp, sinp, qt);
  // B: attention over the 4096 cached positions
  attn4_kernel<<<1024, 128, 0, stream>>>(qt, Kc, Vc, partOh, partM, partL);
  // C: combine + new causal tokens
  combine_kernel<<<512, 64, 0, stream>>>(qt, kraw, vraw, cosp, sinp,
                                         partOh, partM, partL, attn);
  // D: output projection
  gemm3_kernel<<<512, 256, 0, stream>>>(attn, Wo, Wo, Wo, 4096, 0,
                                        out, 4096, out, 4096, out, 4096);
}